// Round 4
// baseline (1652.363 us; speedup 1.0000x reference)
//
#include <hip/hip_runtime.h>
#include <hip/hip_bf16.h>

typedef __attribute__((ext_vector_type(4))) float f32x4;
typedef __attribute__((ext_vector_type(8))) __bf16 bf16x8;

// async 16B global -> LDS (wave-uniform LDS base + lane*16)
__device__ __forceinline__ void gld_lds16(const void* g, void* l) {
  __builtin_amdgcn_global_load_lds((__attribute__((address_space(1))) void*)(g),
                                   (__attribute__((address_space(3))) void*)(l),
                                   16, 0, 0);
}

__device__ __forceinline__ f32x4 mfma16(bf16x8 a, bf16x8 b, f32x4 c) {
  return __builtin_amdgcn_mfma_f32_16x16x32_bf16(a, b, c, 0, 0, 0);
}

// convert 8 fp32 (two f32x4) to bf16x8
__device__ __forceinline__ bf16x8 cvt8(f32x4 a, f32x4 b) {
  bf16x8 r;
  r[0] = (__bf16)a.x; r[1] = (__bf16)a.y; r[2] = (__bf16)a.z; r[3] = (__bf16)a.w;
  r[4] = (__bf16)b.x; r[5] = (__bf16)b.y; r[6] = (__bf16)b.z; r[7] = (__bf16)b.w;
  return r;
}

// scale 8 fp32 by 8 fp32 gates, round once to bf16
__device__ __forceinline__ bf16x8 mulcvt8(f32x4 a, f32x4 b, f32x4 g0, f32x4 g1) {
  bf16x8 r;
  r[0] = (__bf16)(a.x * g0.x); r[1] = (__bf16)(a.y * g0.y);
  r[2] = (__bf16)(a.z * g0.z); r[3] = (__bf16)(a.w * g0.w);
  r[4] = (__bf16)(b.x * g1.x); r[5] = (__bf16)(b.y * g1.y);
  r[6] = (__bf16)(b.z * g1.z); r[7] = (__bf16)(b.w * g1.w);
  return r;
}

// ---------------------------------------------------------------------------
// Transpose + convert 5 weight matrices: fp32 src[k][n] -> bf16 dst[n][k].
// ---------------------------------------------------------------------------
struct P5 {
  const float* s[5];
  __bf16* d[5];
};

__global__ __launch_bounds__(256) void transpose_cvt_k(P5 p) {
  __shared__ __bf16 tile[64][66];  // pad 66: read phase 2-way max (free)
  const float* src = p.s[blockIdx.z];
  __bf16* dst = p.d[blockIdx.z];
  const int x = threadIdx.x & 63, y = threadIdx.x >> 6;
  const int n0 = blockIdx.x * 64, k0 = blockIdx.y * 64;
#pragma unroll
  for (int r = 0; r < 16; ++r) {
    int k = r * 4 + y;
    tile[k][x] = (__bf16)src[(size_t)(k0 + k) * 512 + n0 + x];
  }
  __syncthreads();
#pragma unroll
  for (int r = 0; r < 16; ++r) {
    int n = r * 4 + y;
    dst[(size_t)(n0 + n) * 512 + k0 + x] = tile[x][n];
  }
}

// ---------------------------------------------------------------------------
// Small 512x512x512 GEMM: C = act(A @ B + bias), fp32 in/out, bf16 MFMA.
// Tile 64x64, BK=32, 4 waves each 32x32. act: 0=none, 1=relu, 2=sigmoid.
// ---------------------------------------------------------------------------
struct GemmArgs {
  const float* A;
  const __bf16* Bt;
  const float* bias;
  float* C;
  int act;
};
struct GemmPair { GemmArgs g[2]; };

__device__ __forceinline__ void gemm512_body(const float* __restrict__ A,
                                             const __bf16* __restrict__ Bt,
                                             const float* __restrict__ bias,
                                             float* __restrict__ C, int act,
                                             int bidx) {
  __shared__ alignas(16) __bf16 Als[64 * 32];
  __shared__ alignas(16) __bf16 Bls[64 * 32];
  const int t = threadIdx.x;
  const int w = t >> 6, L = t & 63, lq = L >> 4, l16 = L & 15;
  const int m0 = (bidx & 7) * 64, n0 = (bidx >> 3) * 64;
  const int wm = (w & 1) * 32, wn = (w >> 1) * 32;
  const int row = t >> 2, p = t & 3;
  const int q = p ^ ((row >> 1) & 3);  // logical chunk this lane fetches

  const float* ap = A + (size_t)(m0 + row) * 512 + q * 8;
  const __bf16* bp = Bt + (size_t)(n0 + row) * 512 + q * 8;
  __bf16* aw = &Als[row * 32 + p * 8];
  void* bl = (void*)&Bls[w * 512];
  const int sq8 = (lq ^ ((l16 >> 1) & 3)) * 8;

  const f32x4 fz = {0.f, 0.f, 0.f, 0.f};
  f32x4 acc[2][2] = {{fz, fz}, {fz, fz}};

  for (int kt = 0; kt < 16; ++kt) {
    const int k0 = kt * 32;
    if (kt) __syncthreads();
    f32x4 a0 = *(const f32x4*)(ap + k0);
    f32x4 a1 = *(const f32x4*)(ap + k0 + 4);
    *(bf16x8*)aw = cvt8(a0, a1);
    gld_lds16(bp + k0, bl);
    __syncthreads();
    bf16x8 af[2], bb[2];
#pragma unroll
    for (int mt = 0; mt < 2; ++mt)
      af[mt] = *(const bf16x8*)&Als[(wm + mt * 16 + l16) * 32 + sq8];
#pragma unroll
    for (int nt = 0; nt < 2; ++nt)
      bb[nt] = *(const bf16x8*)&Bls[(wn + nt * 16 + l16) * 32 + sq8];
#pragma unroll
    for (int mt = 0; mt < 2; ++mt)
#pragma unroll
      for (int nt = 0; nt < 2; ++nt)
        acc[mt][nt] = mfma16(af[mt], bb[nt], acc[mt][nt]);
  }

#pragma unroll
  for (int nt = 0; nt < 2; ++nt) {
    const int o = n0 + wn + nt * 16 + l16;
    const float bv = bias[o];
#pragma unroll
    for (int mt = 0; mt < 2; ++mt) {
      const int mb = m0 + wm + mt * 16 + lq * 4;
#pragma unroll
      for (int r = 0; r < 4; ++r) {
        float v = acc[mt][nt][r] + bv;
        if (act == 1) v = fmaxf(v, 0.f);
        else if (act == 2) v = 1.0f / (1.0f + __expf(-v));
        C[(size_t)(mb + r) * 512 + o] = v;
      }
    }
  }
}

__global__ __launch_bounds__(256) void gemm512_one(GemmArgs a) {
  gemm512_body(a.A, a.Bt, a.bias, a.C, a.act, blockIdx.x);
}

__global__ __launch_bounds__(256) void gemm512_two(GemmPair p) {
  GemmArgs a = p.g[blockIdx.y];
  gemm512_body(a.A, a.Bt, a.bias, a.C, a.act, blockIdx.x);
}

// ---------------------------------------------------------------------------
// Row softmax over S then multiply by T: O = softmax(S, axis=1) * T, fp32.
// ---------------------------------------------------------------------------
__global__ __launch_bounds__(256) void softmax_mul_k(const float* __restrict__ S,
                                                     const float* __restrict__ T,
                                                     float* __restrict__ O) {
  const int i = blockIdx.x, t = threadIdx.x, w = t >> 6, L = t & 63;
  __shared__ float red[8];
  float v0 = S[i * 512 + t];
  float v1 = S[i * 512 + 256 + t];
  float m = fmaxf(v0, v1);
  for (int off = 32; off; off >>= 1) m = fmaxf(m, __shfl_xor(m, off));
  if (L == 0) red[w] = m;
  __syncthreads();
  m = fmaxf(fmaxf(red[0], red[1]), fmaxf(red[2], red[3]));
  float e0 = __expf(v0 - m), e1 = __expf(v1 - m);
  float sm = e0 + e1;
  for (int off = 32; off; off >>= 1) sm += __shfl_xor(sm, off);
  if (L == 0) red[4 + w] = sm;
  __syncthreads();
  sm = (red[4] + red[5]) + (red[6] + red[7]);
  const float inv = 1.0f / sm;
  O[i * 512 + t] = e0 * inv * T[i * 512 + t];
  O[i * 512 + 256 + t] = e1 * inv * T[i * 512 + 256 + t];
}

// ---------------------------------------------------------------------------
// Main einsum v3: OUT[i,j,o] = sum_d gate[i,d]*ox[j,d]*Wo[d,o] + bo[o].
// v0-identical math (128x128 tile, BK=32, 4 waves, acc[4][4], same swizzle,
// same scalar epilogue) with two structural changes driven by round-3 PMC
// (MfmaUtil 15%, VALU 16%, HBM 17% => latency/serialization bound):
//  1. Double-buffered LDS, stage(kt+1) issued BEFORE compute(kt), ONE
//     __syncthreads per K-step: the compiler's vmcnt(0) drain before the
//     barrier now lands after ~600cy of compute => gld_lds latency hidden.
//  2. i-batch G=4: block loops 4 consecutive i over the same (j,o) tile
//     (grid 8192->2048). Amortizes prologue 4x; store-drain of i overlaps
//     K-loop of i+1.
// ---------------------------------------------------------------------------
struct AStage {
  f32x4 xa0, xa1, xb0, xb1, g0, g1;
};

__device__ __forceinline__ AStage load_stage(const float* ox0, const float* ox1,
                                             const float* gp, int k0) {
  AStage s;
  s.xa0 = *(const f32x4*)(ox0 + k0); s.xa1 = *(const f32x4*)(ox0 + k0 + 4);
  s.xb0 = *(const f32x4*)(ox1 + k0); s.xb1 = *(const f32x4*)(ox1 + k0 + 4);
  s.g0  = *(const f32x4*)(gp + k0);  s.g1  = *(const f32x4*)(gp + k0 + 4);
  return s;
}

__global__ __launch_bounds__(256, 3) void einsum_v3(
    const float* __restrict__ OX, const float* __restrict__ GATE,
    const __bf16* __restrict__ WOT, const float* __restrict__ BO,
    float* __restrict__ OUT) {
  __shared__ alignas(16) __bf16 Als[2][128 * 32];
  __shared__ alignas(16) __bf16 Bls[2][128 * 32];
  const int t = threadIdx.x;
  const int bx = blockIdx.x;
  const int i0 = (bx >> 4) * 4;          // 128 i-groups of 4
  const int j0 = ((bx >> 2) & 3) * 128;
  const int o0 = (bx & 3) * 128;
  const int w = t >> 6, L = t & 63, lq = L >> 4, l16 = L & 15;
  const int wm = (w & 1) * 64, wn = (w >> 1) * 64;
  const int r0 = t >> 2, p = t & 3;
  const int q = p ^ ((r0 >> 1) & 3);

  const float* ox0 = OX + (size_t)(j0 + r0) * 512 + q * 8;
  const float* ox1 = ox0 + (size_t)64 * 512;
  const __bf16* wo0 = WOT + (size_t)(o0 + r0) * 512 + q * 8;
  const __bf16* wo1 = wo0 + (size_t)64 * 512;
  const int awo = r0 * 32 + p * 8;  // A-write elem offset within buffer
  const int sq8 = (lq ^ ((l16 >> 1) & 3)) * 8;

  for (int g = 0; g < 4; ++g) {
    const float* gp = GATE + (size_t)(i0 + g) * 512 + q * 8;

    const f32x4 fz = {0.f, 0.f, 0.f, 0.f};
    f32x4 acc[4][4];
#pragma unroll
    for (int a = 0; a < 4; ++a)
#pragma unroll
      for (int b = 0; b < 4; ++b) acc[a][b] = fz;

    // Prologue: stage k-step 0 into buf0, prefetch k-step 1 regs.
    AStage S[2];
    S[0] = load_stage(ox0, ox1, gp, 0);
    *(bf16x8*)&Als[0][awo] = mulcvt8(S[0].xa0, S[0].xa1, S[0].g0, S[0].g1);
    *(bf16x8*)&Als[0][awo + 64 * 32] =
        mulcvt8(S[0].xb0, S[0].xb1, S[0].g0, S[0].g1);
    gld_lds16(wo0, (void*)&Bls[0][w * 512]);
    gld_lds16(wo1, (void*)&Bls[0][(w + 4) * 512]);
    S[1] = load_stage(ox0, ox1, gp, 32);
    __syncthreads();

#pragma unroll
    for (int kt = 0; kt < 16; ++kt) {
      const int cb = kt & 1, nb = cb ^ 1;
      // 1) stage NEXT k-step (regs already resident) — latency hides under
      //    this step's compute; drained by the barrier at loop bottom.
      if (kt < 15) {
        *(bf16x8*)&Als[nb][awo] =
            mulcvt8(S[nb].xa0, S[nb].xa1, S[nb].g0, S[nb].g1);
        *(bf16x8*)&Als[nb][awo + 64 * 32] =
            mulcvt8(S[nb].xb0, S[nb].xb1, S[nb].g0, S[nb].g1);
        gld_lds16(wo0 + (kt + 1) * 32, (void*)&Bls[nb][w * 512]);
        gld_lds16(wo1 + (kt + 1) * 32, (void*)&Bls[nb][(w + 4) * 512]);
      }
      // 2) prefetch regs for k-step kt+2 into the set just consumed.
      if (kt < 14) S[cb] = load_stage(ox0, ox1, gp, (kt + 2) * 32);
      // 3) compute current buffer.
      bf16x8 af[4], bb[4];
#pragma unroll
      for (int mt = 0; mt < 4; ++mt)
        af[mt] = *(const bf16x8*)&Als[cb][(wm + mt * 16 + l16) * 32 + sq8];
#pragma unroll
      for (int nt = 0; nt < 4; ++nt)
        bb[nt] = *(const bf16x8*)&Bls[cb][(wn + nt * 16 + l16) * 32 + sq8];
#pragma unroll
      for (int mt = 0; mt < 4; ++mt)
#pragma unroll
        for (int nt = 0; nt < 4; ++nt)
          acc[mt][nt] = mfma16(af[mt], bb[nt], acc[mt][nt]);
      __syncthreads();
    }

    // Epilogue (v0-identical): stores drain while next g computes.
    const size_t obase = (size_t)(i0 + g) * 512 * 512;
#pragma unroll
    for (int nt = 0; nt < 4; ++nt) {
      const int o = o0 + wn + nt * 16 + l16;
      const float bv = BO[o];
#pragma unroll
      for (int mt = 0; mt < 4; ++mt) {
        const int jb = j0 + wm + mt * 16 + lq * 4;
#pragma unroll
        for (int r = 0; r < 4; ++r)
          OUT[obase + (size_t)(jb + r) * 512 + o] = acc[mt][nt][r] + bv;
      }
    }
  }
}

// ---------------------------------------------------------------------------
extern "C" void kernel_launch(void* const* d_in, const int* in_sizes, int n_in,
                              void* d_out, int out_size, void* d_ws, size_t ws_size,
                              hipStream_t stream) {
  (void)in_sizes; (void)n_in; (void)out_size; (void)ws_size;
  const float* image = (const float*)d_in[0];
  const float* text  = (const float*)d_in[1];
  // d_in[2] = cell_id (int, ==1): einsum branch (out_size == 512^3).
  const float* Wx  = (const float*)d_in[3];
  const float* bx  = (const float*)d_in[4];
  const float* Wy  = (const float*)d_in[5];
  const float* by  = (const float*)d_in[6];
  const float* Wo  = (const float*)d_in[7];
  const float* bo  = (const float*)d_in[8];
  const float* Wa1 = (const float*)d_in[9];
  const float* ba1 = (const float*)d_in[10];
  const float* Wa2 = (const float*)d_in[11];
  const float* ba2 = (const float*)d_in[12];

  char* ws = (char*)d_ws;
  const size_t HB = 512 * 1024;   // bf16 512x512 = 512 KB
  const size_t FB = 1024 * 1024;  // fp32 512x512 = 1 MB
  __bf16* tWx  = (__bf16*)(ws + 0 * HB);
  __bf16* tWy  = (__bf16*)(ws + 1 * HB);
  __bf16* tWo  = (__bf16*)(ws + 2 * HB);
  __bf16* tWa1 = (__bf16*)(ws + 3 * HB);
  __bf16* tWa2 = (__bf16*)(ws + 4 * HB);
  char* fb = ws + 5 * HB;
  float* hbuf  = (float*)(fb + 0 * FB);
  float* sbuf  = (float*)(fb + 1 * FB);
  float* t2    = (float*)(fb + 2 * FB);
  float* oxb   = (float*)(fb + 3 * FB);
  float* gateb = (float*)(fb + 4 * FB);

  P5 p;
  p.s[0] = Wx;  p.d[0] = tWx;
  p.s[1] = Wy;  p.d[1] = tWy;
  p.s[2] = Wo;  p.d[2] = tWo;
  p.s[3] = Wa1; p.d[3] = tWa1;
  p.s[4] = Wa2; p.d[4] = tWa2;
  transpose_cvt_k<<<dim3(8, 8, 5), 256, 0, stream>>>(p);

  // h = relu(text @ Wa1 + ba1)  ||  out_x = image @ Wx + bx (independent)
  GemmPair pp;
  pp.g[0] = GemmArgs{text, tWa1, ba1, hbuf, 1};
  pp.g[1] = GemmArgs{image, tWx, bx, oxb, 0};
  gemm512_two<<<dim3(64, 2), 256, 0, stream>>>(pp);
  // s = h @ Wa2 + ba2
  gemm512_one<<<64, 256, 0, stream>>>(GemmArgs{hbuf, tWa2, ba2, sbuf, 0});
  // t2 = softmax(s, axis=1) * text
  softmax_mul_k<<<512, 256, 0, stream>>>(sbuf, text, t2);
  // gate = sigmoid(t2 @ Wy + by)
  gemm512_one<<<64, 256, 0, stream>>>(GemmArgs{t2, tWy, by, gateb, 2});
  // out[i,j,o] = sum_d gate[i,d]*out_x[j,d]*Wo[d,o] + bo[o]
  einsum_v3<<<2048, 256, 0, stream>>>(oxb, gateb, tWo, bo, (float*)d_out);
}

// Round 5
// 1577.477 us; speedup vs baseline: 1.0475x; 1.0475x over previous
//
#include <hip/hip_runtime.h>
#include <hip/hip_bf16.h>

typedef __attribute__((ext_vector_type(4))) float f32x4;
typedef __attribute__((ext_vector_type(8))) __bf16 bf16x8;

// async 16B global -> LDS (wave-uniform LDS base + lane*16)
__device__ __forceinline__ void gld_lds16(const void* g, void* l) {
  __builtin_amdgcn_global_load_lds((__attribute__((address_space(1))) void*)(g),
                                   (__attribute__((address_space(3))) void*)(l),
                                   16, 0, 0);
}

__device__ __forceinline__ f32x4 mfma16(bf16x8 a, bf16x8 b, f32x4 c) {
  return __builtin_amdgcn_mfma_f32_16x16x32_bf16(a, b, c, 0, 0, 0);
}

// convert 8 fp32 (two f32x4) to bf16x8
__device__ __forceinline__ bf16x8 cvt8(f32x4 a, f32x4 b) {
  bf16x8 r;
  r[0] = (__bf16)a.x; r[1] = (__bf16)a.y; r[2] = (__bf16)a.z; r[3] = (__bf16)a.w;
  r[4] = (__bf16)b.x; r[5] = (__bf16)b.y; r[6] = (__bf16)b.z; r[7] = (__bf16)b.w;
  return r;
}

// scale 8 fp32 by 8 fp32 gates, round once to bf16
__device__ __forceinline__ bf16x8 mulcvt8(f32x4 a, f32x4 b, f32x4 g0, f32x4 g1) {
  bf16x8 r;
  r[0] = (__bf16)(a.x * g0.x); r[1] = (__bf16)(a.y * g0.y);
  r[2] = (__bf16)(a.z * g0.z); r[3] = (__bf16)(a.w * g0.w);
  r[4] = (__bf16)(b.x * g1.x); r[5] = (__bf16)(b.y * g1.y);
  r[6] = (__bf16)(b.z * g1.z); r[7] = (__bf16)(b.w * g1.w);
  return r;
}

// ---------------------------------------------------------------------------
// Transpose + convert 5 weight matrices: fp32 src[k][n] -> bf16 dst[n][k].
// ---------------------------------------------------------------------------
struct P5 {
  const float* s[5];
  __bf16* d[5];
};

__global__ __launch_bounds__(256) void transpose_cvt_k(P5 p) {
  __shared__ __bf16 tile[64][66];  // pad 66: read phase 2-way max (free)
  const float* src = p.s[blockIdx.z];
  __bf16* dst = p.d[blockIdx.z];
  const int x = threadIdx.x & 63, y = threadIdx.x >> 6;
  const int n0 = blockIdx.x * 64, k0 = blockIdx.y * 64;
#pragma unroll
  for (int r = 0; r < 16; ++r) {
    int k = r * 4 + y;
    tile[k][x] = (__bf16)src[(size_t)(k0 + k) * 512 + n0 + x];
  }
  __syncthreads();
#pragma unroll
  for (int r = 0; r < 16; ++r) {
    int n = r * 4 + y;
    dst[(size_t)(n0 + n) * 512 + k0 + x] = tile[x][n];
  }
}

// ---------------------------------------------------------------------------
// Small 512x512x512 GEMM: C = act(A @ B + bias), fp32 in/out, bf16 MFMA.
// Tile 64x64, BK=32, 4 waves each 32x32. act: 0=none, 1=relu, 2=sigmoid.
// ---------------------------------------------------------------------------
struct GemmArgs {
  const float* A;
  const __bf16* Bt;
  const float* bias;
  float* C;
  int act;
};
struct GemmPair { GemmArgs g[2]; };

__device__ __forceinline__ void gemm512_body(const float* __restrict__ A,
                                             const __bf16* __restrict__ Bt,
                                             const float* __restrict__ bias,
                                             float* __restrict__ C, int act,
                                             int bidx) {
  __shared__ alignas(16) __bf16 Als[64 * 32];
  __shared__ alignas(16) __bf16 Bls[64 * 32];
  const int t = threadIdx.x;
  const int w = t >> 6, L = t & 63, lq = L >> 4, l16 = L & 15;
  const int m0 = (bidx & 7) * 64, n0 = (bidx >> 3) * 64;
  const int wm = (w & 1) * 32, wn = (w >> 1) * 32;
  const int row = t >> 2, p = t & 3;
  const int q = p ^ ((row >> 1) & 3);  // logical chunk this lane fetches

  const float* ap = A + (size_t)(m0 + row) * 512 + q * 8;
  const __bf16* bp = Bt + (size_t)(n0 + row) * 512 + q * 8;
  __bf16* aw = &Als[row * 32 + p * 8];
  void* bl = (void*)&Bls[w * 512];
  const int sq8 = (lq ^ ((l16 >> 1) & 3)) * 8;

  const f32x4 fz = {0.f, 0.f, 0.f, 0.f};
  f32x4 acc[2][2] = {{fz, fz}, {fz, fz}};

  for (int kt = 0; kt < 16; ++kt) {
    const int k0 = kt * 32;
    if (kt) __syncthreads();
    f32x4 a0 = *(const f32x4*)(ap + k0);
    f32x4 a1 = *(const f32x4*)(ap + k0 + 4);
    *(bf16x8*)aw = cvt8(a0, a1);
    gld_lds16(bp + k0, bl);
    __syncthreads();
    bf16x8 af[2], bb[2];
#pragma unroll
    for (int mt = 0; mt < 2; ++mt)
      af[mt] = *(const bf16x8*)&Als[(wm + mt * 16 + l16) * 32 + sq8];
#pragma unroll
    for (int nt = 0; nt < 2; ++nt)
      bb[nt] = *(const bf16x8*)&Bls[(wn + nt * 16 + l16) * 32 + sq8];
#pragma unroll
    for (int mt = 0; mt < 2; ++mt)
#pragma unroll
      for (int nt = 0; nt < 2; ++nt)
        acc[mt][nt] = mfma16(af[mt], bb[nt], acc[mt][nt]);
  }

#pragma unroll
  for (int nt = 0; nt < 2; ++nt) {
    const int o = n0 + wn + nt * 16 + l16;
    const float bv = bias[o];
#pragma unroll
    for (int mt = 0; mt < 2; ++mt) {
      const int mb = m0 + wm + mt * 16 + lq * 4;
#pragma unroll
      for (int r = 0; r < 4; ++r) {
        float v = acc[mt][nt][r] + bv;
        if (act == 1) v = fmaxf(v, 0.f);
        else if (act == 2) v = 1.0f / (1.0f + __expf(-v));
        C[(size_t)(mb + r) * 512 + o] = v;
      }
    }
  }
}

__global__ __launch_bounds__(256) void gemm512_one(GemmArgs a) {
  gemm512_body(a.A, a.Bt, a.bias, a.C, a.act, blockIdx.x);
}

__global__ __launch_bounds__(256) void gemm512_two(GemmPair p) {
  GemmArgs a = p.g[blockIdx.y];
  gemm512_body(a.A, a.Bt, a.bias, a.C, a.act, blockIdx.x);
}

// ---------------------------------------------------------------------------
// Row softmax over S then multiply by T: O = softmax(S, axis=1) * T, fp32.
// ---------------------------------------------------------------------------
__global__ __launch_bounds__(256) void softmax_mul_k(const float* __restrict__ S,
                                                     const float* __restrict__ T,
                                                     float* __restrict__ O) {
  const int i = blockIdx.x, t = threadIdx.x, w = t >> 6, L = t & 63;
  __shared__ float red[8];
  float v0 = S[i * 512 + t];
  float v1 = S[i * 512 + 256 + t];
  float m = fmaxf(v0, v1);
  for (int off = 32; off; off >>= 1) m = fmaxf(m, __shfl_xor(m, off));
  if (L == 0) red[w] = m;
  __syncthreads();
  m = fmaxf(fmaxf(red[0], red[1]), fmaxf(red[2], red[3]));
  float e0 = __expf(v0 - m), e1 = __expf(v1 - m);
  float sm = e0 + e1;
  for (int off = 32; off; off >>= 1) sm += __shfl_xor(sm, off);
  if (L == 0) red[4 + w] = sm;
  __syncthreads();
  sm = (red[4] + red[5]) + (red[6] + red[7]);
  const float inv = 1.0f / sm;
  O[i * 512 + t] = e0 * inv * T[i * 512 + t];
  O[i * 512 + 256 + t] = e1 * inv * T[i * 512 + 256 + t];
}

// ---------------------------------------------------------------------------
// Main einsum v4: OUT[i,j,o] = sum_d gate[i,d]*ox[j,d]*Wo[d,o] + bo[o].
// v0-identical math (128x128 tile, BK=32, 4 waves, acc[4][4], same swizzle,
// same operand order, same scalar epilogue => same absmax). Structural
// changes vs v0 (v3's design, re-implemented WITHOUT register arrays —
// v3's AStage S[2] went to scratch, 84 VGPR + 1.5 GB scratch fetch):
//  1. Double-buffered LDS, ONE __syncthreads per K-step. Per step kt:
//     issue A-loads(kt+1) + gld_lds B(kt+1)->nb; MFMA on cb (covers the
//     ~200cy L2 latency); cvt+ds_write A(kt+1)->nb; barrier.
//     The prefetch set is ONE named group of 6 f32x4, loaded and consumed
//     in the SAME iteration (no runtime-indexed array -> stays in VGPRs).
//  2. i-batch G=4 (grid 2048): prologue amortized 4x, each g's store
//     drain overlaps g+1's K-loop.
// ---------------------------------------------------------------------------
__global__ __launch_bounds__(256, 3) void einsum_v4(
    const float* __restrict__ OX, const float* __restrict__ GATE,
    const __bf16* __restrict__ WOT, const float* __restrict__ BO,
    float* __restrict__ OUT) {
  __shared__ alignas(16) __bf16 Als[2][128 * 32];
  __shared__ alignas(16) __bf16 Bls[2][128 * 32];
  const int t = threadIdx.x;
  const int bx = blockIdx.x;
  const int i0 = (bx >> 4) * 4;  // 128 i-groups of 4
  const int j0 = ((bx >> 2) & 3) * 128;
  const int o0 = (bx & 3) * 128;
  const int w = t >> 6, L = t & 63, lq = L >> 4, l16 = L & 15;
  const int wm = (w & 1) * 64, wn = (w >> 1) * 64;
  const int r0 = t >> 2, p = t & 3;
  const int q = p ^ ((r0 >> 1) & 3);

  const float* ox0 = OX + (size_t)(j0 + r0) * 512 + q * 8;
  const float* ox1 = ox0 + (size_t)64 * 512;
  const __bf16* wo0 = WOT + (size_t)(o0 + r0) * 512 + q * 8;
  const __bf16* wo1 = wo0 + (size_t)64 * 512;
  const int awo = r0 * 32 + p * 8;  // A-write elem offset within a buffer
  const int sq8 = (lq ^ ((l16 >> 1) & 3)) * 8;

  for (int g = 0; g < 4; ++g) {
    const float* gp = GATE + (size_t)(i0 + g) * 512 + q * 8;

    const f32x4 fz = {0.f, 0.f, 0.f, 0.f};
    f32x4 acc[4][4];
#pragma unroll
    for (int a = 0; a < 4; ++a)
#pragma unroll
      for (int b = 0; b < 4; ++b) acc[a][b] = fz;

    // Prologue: stage K-step 0 into buffer 0.
    {
      f32x4 xa0 = *(const f32x4*)ox0, xa1 = *(const f32x4*)(ox0 + 4);
      f32x4 xb0 = *(const f32x4*)ox1, xb1 = *(const f32x4*)(ox1 + 4);
      f32x4 g0 = *(const f32x4*)gp, g1 = *(const f32x4*)(gp + 4);
      *(bf16x8*)&Als[0][awo] = mulcvt8(xa0, xa1, g0, g1);
      *(bf16x8*)&Als[0][awo + 64 * 32] = mulcvt8(xb0, xb1, g0, g1);
      gld_lds16(wo0, (void*)&Bls[0][w * 512]);
      gld_lds16(wo1, (void*)&Bls[0][(w + 4) * 512]);
    }
    __syncthreads();

#pragma unroll
    for (int kt = 0; kt < 16; ++kt) {
      const int cb = kt & 1, nb = cb ^ 1;
      // 1) Issue next step's global traffic (A to regs, B direct to LDS nb).
      //    Named scalars only — loaded AND consumed within this iteration.
      f32x4 ya0, ya1, yb0, yb1, h0, h1;
      if (kt < 15) {
        const int k1 = (kt + 1) * 32;
        ya0 = *(const f32x4*)(ox0 + k1); ya1 = *(const f32x4*)(ox0 + k1 + 4);
        yb0 = *(const f32x4*)(ox1 + k1); yb1 = *(const f32x4*)(ox1 + k1 + 4);
        h0 = *(const f32x4*)(gp + k1);   h1 = *(const f32x4*)(gp + k1 + 4);
        gld_lds16(wo0 + k1, (void*)&Bls[nb][w * 512]);
        gld_lds16(wo1 + k1, (void*)&Bls[nb][(w + 4) * 512]);
      }
      // 2) Compute current buffer (hides the loads just issued).
      bf16x8 af[4], bb[4];
#pragma unroll
      for (int mt = 0; mt < 4; ++mt)
        af[mt] = *(const bf16x8*)&Als[cb][(wm + mt * 16 + l16) * 32 + sq8];
#pragma unroll
      for (int nt = 0; nt < 4; ++nt)
        bb[nt] = *(const bf16x8*)&Bls[cb][(wn + nt * 16 + l16) * 32 + sq8];
#pragma unroll
      for (int mt = 0; mt < 4; ++mt)
#pragma unroll
        for (int nt = 0; nt < 4; ++nt)
          acc[mt][nt] = mfma16(af[mt], bb[nt], acc[mt][nt]);
      // 3) Write next step's A into nb (loads have landed during compute).
      if (kt < 15) {
        *(bf16x8*)&Als[nb][awo] = mulcvt8(ya0, ya1, h0, h1);
        *(bf16x8*)&Als[nb][awo + 64 * 32] = mulcvt8(yb0, yb1, h0, h1);
      }
      __syncthreads();
    }

    // Epilogue (v0-identical): stores drain while next g computes.
    const size_t obase = (size_t)(i0 + g) * 512 * 512;
#pragma unroll
    for (int nt = 0; nt < 4; ++nt) {
      const int o = o0 + wn + nt * 16 + l16;
      const float bv = BO[o];
#pragma unroll
      for (int mt = 0; mt < 4; ++mt) {
        const int jb = j0 + wm + mt * 16 + lq * 4;
#pragma unroll
        for (int r = 0; r < 4; ++r)
          OUT[obase + (size_t)(jb + r) * 512 + o] = acc[mt][nt][r] + bv;
      }
    }
  }
}

// ---------------------------------------------------------------------------
extern "C" void kernel_launch(void* const* d_in, const int* in_sizes, int n_in,
                              void* d_out, int out_size, void* d_ws, size_t ws_size,
                              hipStream_t stream) {
  (void)in_sizes; (void)n_in; (void)out_size; (void)ws_size;
  const float* image = (const float*)d_in[0];
  const float* text  = (const float*)d_in[1];
  // d_in[2] = cell_id (int, ==1): einsum branch (out_size == 512^3).
  const float* Wx  = (const float*)d_in[3];
  const float* bx  = (const float*)d_in[4];
  const float* Wy  = (const float*)d_in[5];
  const float* by  = (const float*)d_in[6];
  const float* Wo  = (const float*)d_in[7];
  const float* bo  = (const float*)d_in[8];
  const float* Wa1 = (const float*)d_in[9];
  const float* ba1 = (const float*)d_in[10];
  const float* Wa2 = (const float*)d_in[11];
  const float* ba2 = (const float*)d_in[12];

  char* ws = (char*)d_ws;
  const size_t HB = 512 * 1024;   // bf16 512x512 = 512 KB
  const size_t FB = 1024 * 1024;  // fp32 512x512 = 1 MB
  __bf16* tWx  = (__bf16*)(ws + 0 * HB);
  __bf16* tWy  = (__bf16*)(ws + 1 * HB);
  __bf16* tWo  = (__bf16*)(ws + 2 * HB);
  __bf16* tWa1 = (__bf16*)(ws + 3 * HB);
  __bf16* tWa2 = (__bf16*)(ws + 4 * HB);
  char* fb = ws + 5 * HB;
  float* hbuf  = (float*)(fb + 0 * FB);
  float* sbuf  = (float*)(fb + 1 * FB);
  float* t2    = (float*)(fb + 2 * FB);
  float* oxb   = (float*)(fb + 3 * FB);
  float* gateb = (float*)(fb + 4 * FB);

  P5 p;
  p.s[0] = Wx;  p.d[0] = tWx;
  p.s[1] = Wy;  p.d[1] = tWy;
  p.s[2] = Wo;  p.d[2] = tWo;
  p.s[3] = Wa1; p.d[3] = tWa1;
  p.s[4] = Wa2; p.d[4] = tWa2;
  transpose_cvt_k<<<dim3(8, 8, 5), 256, 0, stream>>>(p);

  // h = relu(text @ Wa1 + ba1)  ||  out_x = image @ Wx + bx (independent)
  GemmPair pp;
  pp.g[0] = GemmArgs{text, tWa1, ba1, hbuf, 1};
  pp.g[1] = GemmArgs{image, tWx, bx, oxb, 0};
  gemm512_two<<<dim3(64, 2), 256, 0, stream>>>(pp);
  // s = h @ Wa2 + ba2
  gemm512_one<<<64, 256, 0, stream>>>(GemmArgs{hbuf, tWa2, ba2, sbuf, 0});
  // t2 = softmax(s, axis=1) * text
  softmax_mul_k<<<512, 256, 0, stream>>>(sbuf, text, t2);
  // gate = sigmoid(t2 @ Wy + by)
  gemm512_one<<<64, 256, 0, stream>>>(GemmArgs{t2, tWy, by, gateb, 2});
  // out[i,j,o] = sum_d gate[i,d]*out_x[j,d]*Wo[d,o] + bo[o]
  einsum_v4<<<2048, 256, 0, stream>>>(oxb, gateb, tWo, bo, (float*)d_out);
}